// Round 8
// baseline (231.531 us; speedup 1.0000x reference)
//
#include <hip/hip_runtime.h>

// 3D trilinear grid_sample (border, align_corners=False) of (4,256,256,256) f32
// voxels at N points, + bias. Output (N,4) f32.
//
// R8: double-buffered async tile pipeline. Tiles = 7z x 7y x 64x (37*37*4 =
// 5476). Persistent 256 blocks x 1024 thr; two 64 KB f32 LDS buffers; stage
// via global_load_lds (width 4, per-lane global addr, linear LDS dst): issue
// tile t+1's loads BEFORE sampling tile t -> HBM streams during sampling
// (fixes R6/R7's strict stage/sample alternation, the 2x-over-floor cost).
// LDS layout [row(8z*8y)][c][x=lane]: chunk q <-> LDS dwords q*64, global
// reads perfectly coalesced 256 B/wave, no index division. Points whose
// x-pair crosses a 64-col boundary (xb&63==63, ~1.2%) and bin-overflow points
// are sampled directly in the bin pass (no point can be dropped). All-f32,
// identical fmaf ordering on every path -> deterministic output.

#define SIDE 256
#define CHAN_STRIDE ((size_t)SIDE * SIDE * SIDE)
#define ZR 7
#define YR 7
#define NTZ 37
#define NTY 37
#define NTX 4
#define NTILES (NTZ * NTY * NTX)    // 5476
#define CNT_STRIDE 16               // ints -> 64 B per counter
#define CNT_BYTES (NTILES * CNT_STRIDE * 4)
#define PPT 8                       // points per thread in bin pass
#define CAP 768                     // worst-tile mean ~432 (+16 sigma); overflow safe
#define TILE_DW 16384               // 64 rows * 4 ch * 64 x  (f32 dwords, 64 KB)

typedef float f2_unal __attribute__((ext_vector_type(2), aligned(4)));

typedef const __attribute__((address_space(1))) unsigned int guint;
typedef __attribute__((address_space(3))) unsigned int luint;

__device__ __forceinline__ void async_ld(const float* g, float* l) {
    // one dword per lane; HW writes LDS at (uniform base + lane*4)
    __builtin_amdgcn_global_load_lds((guint*)g, (luint*)l, 4, 0, 0);
}

// ---------------- f32 global sampling (R1, proven) -------------------------
__device__ __forceinline__ float4 sample_one(
    float px, float py, float pz,
    const float* __restrict__ vox, float4 bias)
{
    float ix = fminf(fmaxf(fmaf(px, 128.0f, 127.5f), 0.0f), 255.0f);
    float iy = fminf(fmaxf(fmaf(py, 128.0f, 127.5f), 0.0f), 255.0f);
    float iz = fminf(fmaxf(fmaf(pz, 128.0f, 127.5f), 0.0f), 255.0f);
    float fx = floorf(ix), fy = floorf(iy), fz = floorf(iz);
    float wx = ix - fx, wy = iy - fy, wz = iz - fz;
    int x0 = (int)fx, y0 = (int)fy, z0 = (int)fz;
    int xb = min(x0, SIDE - 2);
    bool xhi = (x0 > xb);
    int y1 = min(y0 + 1, SIDE - 1);
    int z1 = min(z0 + 1, SIDE - 1);
    float ux = 1.0f - wx, uy = 1.0f - wy, uz = 1.0f - wz;
    float w00 = uz * uy, w01 = uz * wy, w10 = wz * uy, w11 = wz * wy;
    size_t b00 = ((size_t)(z0 * SIDE + y0)) * SIDE + xb;
    size_t b01 = ((size_t)(z0 * SIDE + y1)) * SIDE + xb;
    size_t b10 = ((size_t)(z1 * SIDE + y0)) * SIDE + xb;
    size_t b11 = ((size_t)(z1 * SIDE + y1)) * SIDE + xb;
    float r[4];
#pragma unroll
    for (int c = 0; c < 4; ++c) {
        const float* v = vox + (size_t)c * CHAN_STRIDE;
        f2_unal q00 = *(const f2_unal*)(v + b00);
        f2_unal q01 = *(const f2_unal*)(v + b01);
        f2_unal q10 = *(const f2_unal*)(v + b10);
        f2_unal q11 = *(const f2_unal*)(v + b11);
        float a00 = xhi ? q00.y : q00.x;
        float a01 = xhi ? q01.y : q01.x;
        float a10 = xhi ? q10.y : q10.x;
        float a11 = xhi ? q11.y : q11.x;
        r[c] = w00 * fmaf(a00, ux, q00.y * wx)
             + w01 * fmaf(a01, ux, q01.y * wx)
             + w10 * fmaf(a10, ux, q10.y * wx)
             + w11 * fmaf(a11, ux, q11.y * wx);
    }
    return make_float4(r[0] + bias.x, r[1] + bias.y, r[2] + bias.z, r[3] + bias.w);
}

// ---------------- pass 1: bin points by (z/7, y/7, x/64) tile --------------
__global__ __launch_bounds__(256) void bin_kernel(
    const float* __restrict__ pos, int n,
    int* __restrict__ gcnt, uint4* __restrict__ recs,
    const float* __restrict__ vox, const float* __restrict__ biasp,
    float4* __restrict__ out)
{
    __shared__ int hist[NTILES];
    __shared__ int base[NTILES];
    int tid = threadIdx.x;
    for (int b = tid; b < NTILES; b += 256) hist[b] = 0;
    __syncthreads();

    size_t start = ((size_t)blockIdx.x * 256 + tid) * PPT;
    float buf[3 * PPT];
    bool full = (start + PPT <= (size_t)n);
    if (full) {
        const float4* p4 = (const float4*)(pos + 3 * start);  // 96B, 16B-aligned
#pragma unroll
        for (int k = 0; k < 3 * PPT / 4; ++k) ((float4*)buf)[k] = p4[k];
    } else {
#pragma unroll
        for (int k = 0; k < 3 * PPT; ++k) {
            size_t e = 3 * start + k;
            buf[k] = (e < 3 * (size_t)n) ? pos[e] : 0.0f;
        }
    }

    int bin[PPT], rank[PPT];
#pragma unroll
    for (int j = 0; j < PPT; ++j) {
        bin[j] = -1;
        if (start + j < (size_t)n) {
            float px = buf[3 * j + 0];
            float py = buf[3 * j + 1];
            float pz = buf[3 * j + 2];
            float ixf = fminf(fmaxf(fmaf(px, 128.0f, 127.5f), 0.0f), 255.0f);
            float iyf = fminf(fmaxf(fmaf(py, 128.0f, 127.5f), 0.0f), 255.0f);
            float izf = fminf(fmaxf(fmaf(pz, 128.0f, 127.5f), 0.0f), 255.0f);
            int x0 = (int)floorf(ixf);
            int y0 = (int)floorf(iyf);
            int z0 = (int)floorf(izf);
            int xb = min(x0, SIDE - 2);
            if ((xb & 63) == 63) {
                bin[j] = -2;   // x-pair crosses tile boundary: direct sample
            } else {
                bin[j] = ((z0 / ZR) * NTY + (y0 / YR)) * NTX + (xb >> 6);
                rank[j] = atomicAdd(&hist[bin[j]], 1);
            }
        }
    }
    __syncthreads();
    for (int b = tid; b < NTILES; b += 256)
        base[b] = hist[b] ? atomicAdd(&gcnt[b * CNT_STRIDE], hist[b]) : 0;
    __syncthreads();

    float4 bias = *(const float4*)biasp;
#pragma unroll
    for (int j = 0; j < PPT; ++j) {
        if (bin[j] == -1) continue;
        if (bin[j] >= 0) {
            int slot = base[bin[j]] + rank[j];
            if (slot < CAP) {
                uint4 r;
                r.x = __float_as_uint(buf[3 * j + 0]);
                r.y = __float_as_uint(buf[3 * j + 1]);
                r.z = __float_as_uint(buf[3 * j + 2]);
                r.w = (unsigned)(start + j);
                recs[(size_t)bin[j] * CAP + slot] = r;
                continue;
            }
        }
        // crossing or overflow: sample directly -- no point dropped
        out[start + j] = sample_one(buf[3 * j + 0], buf[3 * j + 1],
                                    buf[3 * j + 2], vox, bias);
    }
}

// ---------------- pass 2: dbuf async-staged tile sampling ------------------
__global__ __launch_bounds__(1024) void sample_tiles_kernel(
    const uint4* __restrict__ recs, const int* __restrict__ gcnt,
    const float* __restrict__ vox, const float* __restrict__ biasp,
    float4* __restrict__ out)
{
    __shared__ float buf[2][TILE_DW];   // 2 x 64 KB

    float4 bias = *(const float4*)biasp;
    int tid = threadIdx.x;
    int wave = tid >> 6, lane = tid & 63;

    // stage tile t into buffer b: 256 chunks of 64 dwords; wave w does
    // chunks [w*16, w*16+16). chunk q: row=q>>2 (8z*8y), c=q&3, x=lane.
    auto stage = [&](int t, int b) {
        int xt = t & (NTX - 1);
        int rest = t >> 2;
        int zt = rest / NTY, yt = rest - zt * NTY;
        int zbase = zt * ZR, ybase = yt * YR;
        int xbase = xt << 6;
#pragma unroll
        for (int k = 0; k < 16; ++k) {
            int q = wave * 16 + k;
            int row = q >> 2, c = q & 3;
            int zp = min(zbase + (row >> 3), SIDE - 1);
            int yp = min(ybase + (row & 7), SIDE - 1);
            const float* g = vox + (size_t)c * CHAN_STRIDE
                           + (size_t)(zp * SIDE + yp) * SIDE + xbase + lane;
            async_ld(g, &buf[b][q * 64]);
        }
    };

    int t = blockIdx.x;
    int cur = 0;

    // prologue
    stage(t, 0);
    int cnt = min(gcnt[t * CNT_STRIDE], CAP);
    bool have = tid < cnt;
    uint4 R;
    if (have) R = recs[(size_t)t * CAP + tid];
    __syncthreads();   // drains stage loads (vmcnt) + rec

    while (true) {
        int tn = t + (int)gridDim.x;
        int cnt_n = 0; bool have_n = false; uint4 Rn;
        if (tn < NTILES) {
            stage(tn, cur ^ 1);               // async: flies during sampling
            cnt_n = min(gcnt[tn * CNT_STRIDE], CAP);
            have_n = tid < cnt_n;
            if (have_n) Rn = recs[(size_t)tn * CAP + tid];
        }

        if (have) {
            int xt = t & (NTX - 1);
            int rest = t >> 2;
            int zt = rest / NTY, yt = rest - zt * NTY;
            int zbase = zt * ZR, ybase = yt * YR;
            int xbase = xt << 6;

            float px = __uint_as_float(R.x);
            float py = __uint_as_float(R.y);
            float pz = __uint_as_float(R.z);

            float ix = fminf(fmaxf(fmaf(px, 128.0f, 127.5f), 0.0f), 255.0f);
            float iy = fminf(fmaxf(fmaf(py, 128.0f, 127.5f), 0.0f), 255.0f);
            float iz = fminf(fmaxf(fmaf(pz, 128.0f, 127.5f), 0.0f), 255.0f);
            float fx = floorf(ix), fy = floorf(iy), fz = floorf(iz);
            float wx = ix - fx, wy = iy - fy, wz = iz - fz;
            int x0 = (int)fx, y0 = (int)fy, z0 = (int)fz;
            int xb = min(x0, SIDE - 2);
            bool xhi = (x0 > xb);
            int y1 = min(y0 + 1, SIDE - 1);
            int z1 = min(z0 + 1, SIDE - 1);

            int zl = z0 - zbase, zl1 = z1 - zbase;   // 0..7 staged
            int yl = y0 - ybase, yl1 = y1 - ybase;   // 0..7 staged
            int xo = xb - xbase;                     // 0..62

            int r00 = zl  * 8 + yl,  r01 = zl  * 8 + yl1;
            int r10 = zl1 * 8 + yl,  r11 = zl1 * 8 + yl1;

            float ux = 1.0f - wx, uy = 1.0f - wy, uz = 1.0f - wz;
            float w00 = uz * uy, w01 = uz * wy, w10 = wz * uy, w11 = wz * wy;

            const float* Bf = &buf[cur][0];
            float racc[4];
#pragma unroll
            for (int c = 0; c < 4; ++c) {
                f2_unal q00 = *(const f2_unal*)(Bf + (r00 * 4 + c) * 64 + xo);
                f2_unal q01 = *(const f2_unal*)(Bf + (r01 * 4 + c) * 64 + xo);
                f2_unal q10 = *(const f2_unal*)(Bf + (r10 * 4 + c) * 64 + xo);
                f2_unal q11 = *(const f2_unal*)(Bf + (r11 * 4 + c) * 64 + xo);
                float a00 = xhi ? q00.y : q00.x;
                float a01 = xhi ? q01.y : q01.x;
                float a10 = xhi ? q10.y : q10.x;
                float a11 = xhi ? q11.y : q11.x;
                racc[c] = w00 * fmaf(a00, ux, q00.y * wx)
                        + w01 * fmaf(a01, ux, q01.y * wx)
                        + w10 * fmaf(a10, ux, q10.y * wx)
                        + w11 * fmaf(a11, ux, q11.y * wx);
            }
            out[R.w] = make_float4(racc[0] + bias.x, racc[1] + bias.y,
                                   racc[2] + bias.z, racc[3] + bias.w);
        }

        if (tn >= NTILES) break;
        __syncthreads();       // next buffer staged + everyone done reading cur
        cur ^= 1; t = tn; cnt = cnt_n; have = have_n; R = Rn;
    }
}

// ---------------- fallback: direct (R1, 636 us) ----------------------------
__global__ __launch_bounds__(256) void vox_trilerp_kernel(
    const float* __restrict__ pos, const float* __restrict__ vox,
    const float* __restrict__ biasp, float* __restrict__ out, int n)
{
    int i = blockIdx.x * blockDim.x + threadIdx.x;
    if (i >= n) return;
    float4 bias = *(const float4*)biasp;
    float4 res = sample_one(pos[3 * (size_t)i], pos[3 * (size_t)i + 1],
                            pos[3 * (size_t)i + 2], vox, bias);
    *(float4*)(out + 4 * (size_t)i) = res;
}

extern "C" void kernel_launch(void* const* d_in, const int* in_sizes, int n_in,
                              void* d_out, int out_size, void* d_ws, size_t ws_size,
                              hipStream_t stream) {
    const float* pos  = (const float*)d_in[0];
    const float* vox  = (const float*)d_in[1];
    const float* bias = (const float*)d_in[2];
    float* out = (float*)d_out;

    int n = in_sizes[0] / 3;
    size_t need = (size_t)CNT_BYTES + (size_t)NTILES * CAP * sizeof(uint4); // ~67.6 MB

    if (ws_size >= need && n >= 256 * PPT) {
        int* gcnt = (int*)d_ws;
        uint4* recs = (uint4*)((char*)d_ws + CNT_BYTES);
        hipMemsetAsync(d_ws, 0, CNT_BYTES, stream);
        int grid1 = (n + 256 * PPT - 1) / (256 * PPT);
        bin_kernel<<<grid1, 256, 0, stream>>>(pos, n, gcnt, recs, vox, bias,
                                              (float4*)out);
        sample_tiles_kernel<<<256, 1024, 0, stream>>>(recs, gcnt, vox, bias,
                                                      (float4*)out);
    } else {
        int grid = (n + 255) / 256;
        vox_trilerp_kernel<<<grid, 256, 0, stream>>>(pos, vox, bias, out, n);
    }
}

// Round 9
// 230.735 us; speedup vs baseline: 1.0034x; 1.0034x over previous
//
#include <hip/hip_runtime.h>

// 3D trilinear grid_sample (border, align_corners=False) of (4,256,256,256) f32
// voxels at N points, + bias. Output (N,4) f32.
//
// R9: R8's double-buffered async tile pipeline with the staging width fixed:
// global_load_lds WIDTH 16 (was 4). Guide m193: width 4->16 is a 1.67x lever
// on staging-bound kernels; staging (350 MB) dominates here. Per wave only 4
// async instrs/tile: chunk = 64 lanes x 16 B = 1 KB = 4 LDS sub-rows; lane i
// supplies dwords 4i..4i+3 = sub-row (i>>4), x-dword 4*(i&15). LDS dst linear
// (wave-uniform base + lane*16, rule 21). Everything else identical to R8
// (tiles 7z x 7y x 64x = 5476, 64 KB f32 tiles, 2-deep dbuf, crossing/overflow
// points sampled directly in bin pass, all-f32 deterministic).

#define SIDE 256
#define CHAN_STRIDE ((size_t)SIDE * SIDE * SIDE)
#define ZR 7
#define YR 7
#define NTZ 37
#define NTY 37
#define NTX 4
#define NTILES (NTZ * NTY * NTX)    // 5476
#define CNT_STRIDE 16               // ints -> 64 B per counter
#define CNT_BYTES (NTILES * CNT_STRIDE * 4)
#define PPT 8                       // points per thread in bin pass
#define CAP 768                     // worst-tile mean ~456; overflow safe anyway
#define TILE_DW 16384               // 64 rows * 4 ch * 64 x  (f32 dwords, 64 KB)

typedef float f2_unal __attribute__((ext_vector_type(2), aligned(4)));

typedef const __attribute__((address_space(1))) unsigned int guint;
typedef __attribute__((address_space(3))) unsigned int luint;

__device__ __forceinline__ void async_ld16(const float* g, float* l) {
    // 16 B per lane; HW writes LDS at (wave-uniform base + lane*16)
    __builtin_amdgcn_global_load_lds((guint*)g, (luint*)l, 16, 0, 0);
}

// ---------------- f32 global sampling (R1, proven) -------------------------
__device__ __forceinline__ float4 sample_one(
    float px, float py, float pz,
    const float* __restrict__ vox, float4 bias)
{
    float ix = fminf(fmaxf(fmaf(px, 128.0f, 127.5f), 0.0f), 255.0f);
    float iy = fminf(fmaxf(fmaf(py, 128.0f, 127.5f), 0.0f), 255.0f);
    float iz = fminf(fmaxf(fmaf(pz, 128.0f, 127.5f), 0.0f), 255.0f);
    float fx = floorf(ix), fy = floorf(iy), fz = floorf(iz);
    float wx = ix - fx, wy = iy - fy, wz = iz - fz;
    int x0 = (int)fx, y0 = (int)fy, z0 = (int)fz;
    int xb = min(x0, SIDE - 2);
    bool xhi = (x0 > xb);
    int y1 = min(y0 + 1, SIDE - 1);
    int z1 = min(z0 + 1, SIDE - 1);
    float ux = 1.0f - wx, uy = 1.0f - wy, uz = 1.0f - wz;
    float w00 = uz * uy, w01 = uz * wy, w10 = wz * uy, w11 = wz * wy;
    size_t b00 = ((size_t)(z0 * SIDE + y0)) * SIDE + xb;
    size_t b01 = ((size_t)(z0 * SIDE + y1)) * SIDE + xb;
    size_t b10 = ((size_t)(z1 * SIDE + y0)) * SIDE + xb;
    size_t b11 = ((size_t)(z1 * SIDE + y1)) * SIDE + xb;
    float r[4];
#pragma unroll
    for (int c = 0; c < 4; ++c) {
        const float* v = vox + (size_t)c * CHAN_STRIDE;
        f2_unal q00 = *(const f2_unal*)(v + b00);
        f2_unal q01 = *(const f2_unal*)(v + b01);
        f2_unal q10 = *(const f2_unal*)(v + b10);
        f2_unal q11 = *(const f2_unal*)(v + b11);
        float a00 = xhi ? q00.y : q00.x;
        float a01 = xhi ? q01.y : q01.x;
        float a10 = xhi ? q10.y : q10.x;
        float a11 = xhi ? q11.y : q11.x;
        r[c] = w00 * fmaf(a00, ux, q00.y * wx)
             + w01 * fmaf(a01, ux, q01.y * wx)
             + w10 * fmaf(a10, ux, q10.y * wx)
             + w11 * fmaf(a11, ux, q11.y * wx);
    }
    return make_float4(r[0] + bias.x, r[1] + bias.y, r[2] + bias.z, r[3] + bias.w);
}

// ---------------- pass 1: bin points by (z/7, y/7, x/64) tile --------------
__global__ __launch_bounds__(256) void bin_kernel(
    const float* __restrict__ pos, int n,
    int* __restrict__ gcnt, uint4* __restrict__ recs,
    const float* __restrict__ vox, const float* __restrict__ biasp,
    float4* __restrict__ out)
{
    __shared__ int hist[NTILES];
    __shared__ int base[NTILES];
    int tid = threadIdx.x;
    for (int b = tid; b < NTILES; b += 256) hist[b] = 0;
    __syncthreads();

    size_t start = ((size_t)blockIdx.x * 256 + tid) * PPT;
    float buf[3 * PPT];
    bool full = (start + PPT <= (size_t)n);
    if (full) {
        const float4* p4 = (const float4*)(pos + 3 * start);  // 96B, 16B-aligned
#pragma unroll
        for (int k = 0; k < 3 * PPT / 4; ++k) ((float4*)buf)[k] = p4[k];
    } else {
#pragma unroll
        for (int k = 0; k < 3 * PPT; ++k) {
            size_t e = 3 * start + k;
            buf[k] = (e < 3 * (size_t)n) ? pos[e] : 0.0f;
        }
    }

    int bin[PPT], rank[PPT];
#pragma unroll
    for (int j = 0; j < PPT; ++j) {
        bin[j] = -1;
        if (start + j < (size_t)n) {
            float px = buf[3 * j + 0];
            float py = buf[3 * j + 1];
            float pz = buf[3 * j + 2];
            float ixf = fminf(fmaxf(fmaf(px, 128.0f, 127.5f), 0.0f), 255.0f);
            float iyf = fminf(fmaxf(fmaf(py, 128.0f, 127.5f), 0.0f), 255.0f);
            float izf = fminf(fmaxf(fmaf(pz, 128.0f, 127.5f), 0.0f), 255.0f);
            int x0 = (int)floorf(ixf);
            int y0 = (int)floorf(iyf);
            int z0 = (int)floorf(izf);
            int xb = min(x0, SIDE - 2);
            if ((xb & 63) == 63) {
                bin[j] = -2;   // x-pair crosses tile boundary: direct sample
            } else {
                bin[j] = ((z0 / ZR) * NTY + (y0 / YR)) * NTX + (xb >> 6);
                rank[j] = atomicAdd(&hist[bin[j]], 1);
            }
        }
    }
    __syncthreads();
    for (int b = tid; b < NTILES; b += 256)
        base[b] = hist[b] ? atomicAdd(&gcnt[b * CNT_STRIDE], hist[b]) : 0;
    __syncthreads();

    float4 bias = *(const float4*)biasp;
#pragma unroll
    for (int j = 0; j < PPT; ++j) {
        if (bin[j] == -1) continue;
        if (bin[j] >= 0) {
            int slot = base[bin[j]] + rank[j];
            if (slot < CAP) {
                uint4 r;
                r.x = __float_as_uint(buf[3 * j + 0]);
                r.y = __float_as_uint(buf[3 * j + 1]);
                r.z = __float_as_uint(buf[3 * j + 2]);
                r.w = (unsigned)(start + j);
                recs[(size_t)bin[j] * CAP + slot] = r;
                continue;
            }
        }
        // crossing or overflow: sample directly -- no point dropped
        out[start + j] = sample_one(buf[3 * j + 0], buf[3 * j + 1],
                                    buf[3 * j + 2], vox, bias);
    }
}

// ---------------- pass 2: dbuf async-staged tile sampling ------------------
__global__ __launch_bounds__(1024) void sample_tiles_kernel(
    const uint4* __restrict__ recs, const int* __restrict__ gcnt,
    const float* __restrict__ vox, const float* __restrict__ biasp,
    float4* __restrict__ out)
{
    __shared__ float buf[2][TILE_DW];   // 2 x 64 KB

    float4 bias = *(const float4*)biasp;
    int tid = threadIdx.x;
    int wave = tid >> 6, lane = tid & 63;

    // stage tile t into buffer b: 64 chunks of 1 KB (width-16 async); wave w
    // does chunks [w*4, w*4+4). Chunk q covers LDS dwords [q*256, q*256+256)
    // = sub-rows 4q..4q+3 (sub-row s: row=s>>2 (8z*8y), c=s&3, 64 x-dwords).
    // Lane i supplies sub-row 4q+(i>>4), x-dwords 4*(i&15)..+3.
    auto stage = [&](int t, int b) {
        int xt = t & (NTX - 1);
        int rest = t >> 2;
        int zt = rest / NTY, yt = rest - zt * NTY;
        int zbase = zt * ZR, ybase = yt * YR;
        int xbase = xt << 6;
        int ls = lane >> 4;            // sub-row offset within chunk
        int lx = (lane & 15) << 2;     // x-dword offset
#pragma unroll
        for (int k = 0; k < 4; ++k) {
            int q = wave * 4 + k;
            int s = 4 * q + ls;        // sub-row 0..255
            int row = s >> 2, c = s & 3;
            int zp = min(zbase + (row >> 3), SIDE - 1);
            int yp = min(ybase + (row & 7), SIDE - 1);
            const float* g = vox + (size_t)c * CHAN_STRIDE
                           + (size_t)(zp * SIDE + yp) * SIDE + xbase + lx;
            async_ld16(g, &buf[b][q * 256]);
        }
    };

    int t = blockIdx.x;
    int cur = 0;

    // prologue
    stage(t, 0);
    int cnt = min(gcnt[t * CNT_STRIDE], CAP);
    bool have = tid < cnt;
    uint4 R;
    if (have) R = recs[(size_t)t * CAP + tid];
    __syncthreads();   // drains stage loads (vmcnt) + rec

    while (true) {
        int tn = t + (int)gridDim.x;
        int cnt_n = 0; bool have_n = false; uint4 Rn;
        if (tn < NTILES) {
            stage(tn, cur ^ 1);               // async: flies during sampling
            cnt_n = min(gcnt[tn * CNT_STRIDE], CAP);
            have_n = tid < cnt_n;
            if (have_n) Rn = recs[(size_t)tn * CAP + tid];
        }

        if (have) {
            int xt = t & (NTX - 1);
            int rest = t >> 2;
            int zt = rest / NTY, yt = rest - zt * NTY;
            int zbase = zt * ZR, ybase = yt * YR;
            int xbase = xt << 6;

            float px = __uint_as_float(R.x);
            float py = __uint_as_float(R.y);
            float pz = __uint_as_float(R.z);

            float ix = fminf(fmaxf(fmaf(px, 128.0f, 127.5f), 0.0f), 255.0f);
            float iy = fminf(fmaxf(fmaf(py, 128.0f, 127.5f), 0.0f), 255.0f);
            float iz = fminf(fmaxf(fmaf(pz, 128.0f, 127.5f), 0.0f), 255.0f);
            float fx = floorf(ix), fy = floorf(iy), fz = floorf(iz);
            float wx = ix - fx, wy = iy - fy, wz = iz - fz;
            int x0 = (int)fx, y0 = (int)fy, z0 = (int)fz;
            int xb = min(x0, SIDE - 2);
            bool xhi = (x0 > xb);
            int y1 = min(y0 + 1, SIDE - 1);
            int z1 = min(z0 + 1, SIDE - 1);

            int zl = z0 - zbase, zl1 = z1 - zbase;   // 0..7 staged
            int yl = y0 - ybase, yl1 = y1 - ybase;   // 0..7 staged
            int xo = xb - xbase;                     // 0..62

            int r00 = zl  * 8 + yl,  r01 = zl  * 8 + yl1;
            int r10 = zl1 * 8 + yl,  r11 = zl1 * 8 + yl1;

            float ux = 1.0f - wx, uy = 1.0f - wy, uz = 1.0f - wz;
            float w00 = uz * uy, w01 = uz * wy, w10 = wz * uy, w11 = wz * wy;

            const float* Bf = &buf[cur][0];
            float racc[4];
#pragma unroll
            for (int c = 0; c < 4; ++c) {
                f2_unal q00 = *(const f2_unal*)(Bf + (r00 * 4 + c) * 64 + xo);
                f2_unal q01 = *(const f2_unal*)(Bf + (r01 * 4 + c) * 64 + xo);
                f2_unal q10 = *(const f2_unal*)(Bf + (r10 * 4 + c) * 64 + xo);
                f2_unal q11 = *(const f2_unal*)(Bf + (r11 * 4 + c) * 64 + xo);
                float a00 = xhi ? q00.y : q00.x;
                float a01 = xhi ? q01.y : q01.x;
                float a10 = xhi ? q10.y : q10.x;
                float a11 = xhi ? q11.y : q11.x;
                racc[c] = w00 * fmaf(a00, ux, q00.y * wx)
                        + w01 * fmaf(a01, ux, q01.y * wx)
                        + w10 * fmaf(a10, ux, q10.y * wx)
                        + w11 * fmaf(a11, ux, q11.y * wx);
            }
            out[R.w] = make_float4(racc[0] + bias.x, racc[1] + bias.y,
                                   racc[2] + bias.z, racc[3] + bias.w);
        }

        if (tn >= NTILES) break;
        __syncthreads();       // next buffer staged + everyone done reading cur
        cur ^= 1; t = tn; cnt = cnt_n; have = have_n; R = Rn;
    }
}

// ---------------- fallback: direct (R1, 636 us) ----------------------------
__global__ __launch_bounds__(256) void vox_trilerp_kernel(
    const float* __restrict__ pos, const float* __restrict__ vox,
    const float* __restrict__ biasp, float* __restrict__ out, int n)
{
    int i = blockIdx.x * blockDim.x + threadIdx.x;
    if (i >= n) return;
    float4 bias = *(const float4*)biasp;
    float4 res = sample_one(pos[3 * (size_t)i], pos[3 * (size_t)i + 1],
                            pos[3 * (size_t)i + 2], vox, bias);
    *(float4*)(out + 4 * (size_t)i) = res;
}

extern "C" void kernel_launch(void* const* d_in, const int* in_sizes, int n_in,
                              void* d_out, int out_size, void* d_ws, size_t ws_size,
                              hipStream_t stream) {
    const float* pos  = (const float*)d_in[0];
    const float* vox  = (const float*)d_in[1];
    const float* bias = (const float*)d_in[2];
    float* out = (float*)d_out;

    int n = in_sizes[0] / 3;
    size_t need = (size_t)CNT_BYTES + (size_t)NTILES * CAP * sizeof(uint4); // ~67.6 MB

    if (ws_size >= need && n >= 256 * PPT) {
        int* gcnt = (int*)d_ws;
        uint4* recs = (uint4*)((char*)d_ws + CNT_BYTES);
        hipMemsetAsync(d_ws, 0, CNT_BYTES, stream);
        int grid1 = (n + 256 * PPT - 1) / (256 * PPT);
        bin_kernel<<<grid1, 256, 0, stream>>>(pos, n, gcnt, recs, vox, bias,
                                              (float4*)out);
        sample_tiles_kernel<<<256, 1024, 0, stream>>>(recs, gcnt, vox, bias,
                                                      (float4*)out);
    } else {
        int grid = (n + 255) / 256;
        vox_trilerp_kernel<<<grid, 256, 0, stream>>>(pos, vox, bias, out, n);
    }
}

// Round 10
// 193.399 us; speedup vs baseline: 1.1972x; 1.1931x over previous
//
#include <hip/hip_runtime.h>

// 3D trilinear grid_sample (border, align_corners=False) of (4,256,256,256) f32
// voxels at N points, + bias. Output (N,4) f32.
//
// R10: R6's proven tile-and-stage structure, re-parametrized for 2 blocks/CU.
// Tiles = (z/7, y/7, x-half): 37*37*2 = 2738. Each 512-thread block stages its
// 8z x 8y x 130x x 4ch sub-volume f32->fp16 into a 65 KB LDS tile, then
// samples its points from LDS. 2 x 65 KB = 130 KB <= 160 KB and
// __launch_bounds__(512,4) caps VGPR at 128 (no spills, unlike R7's
// (1024,8) -> VGPR 64 -> scratch) -> TWO co-resident blocks per CU: one
// stages (HBM) while the other samples (LDS/VALU), block turnover keeps the
// pipe fed. R8/R9 post-mortem: explicit dbuf with tiny tiles lost to per-tile
// fixed costs + 5476-bin binning; this keeps R6's cheap 1-tile-per-block
// shape. Overflow points sampled directly in bin pass (nothing dropped).

#define SIDE 256
#define CHAN_STRIDE ((size_t)SIDE * SIDE * SIDE)
#define ZR 7
#define YR 7
#define NTZ 37
#define NTY 37
#define NTILES (NTZ * NTY * 2)      // 2738 (x split in halves)
#define COLS 130                    // staged x-columns (128 + 2 halo)
#define ROWS 64                     // 8 z-planes x 8 y-rows
#define CNT_STRIDE 16               // ints -> 64 B per counter
#define CNT_BYTES (NTILES * CNT_STRIDE * 4)
#define PPT 8                       // points per thread in bin pass
#define CAP 1280                    // corner-tile mean 858 (+14 sigma); overflow safe
#define BLK 512

typedef float f2_unal __attribute__((ext_vector_type(2), aligned(4)));
typedef _Float16 h8_lds __attribute__((ext_vector_type(8), aligned(8)));
typedef _Float16 h8_al  __attribute__((ext_vector_type(8), aligned(16)));

// ---------------- f32 global sampling (R1, proven) -------------------------
__device__ __forceinline__ float4 sample_one(
    float px, float py, float pz,
    const float* __restrict__ vox, float4 bias)
{
    float ix = fminf(fmaxf(fmaf(px, 128.0f, 127.5f), 0.0f), 255.0f);
    float iy = fminf(fmaxf(fmaf(py, 128.0f, 127.5f), 0.0f), 255.0f);
    float iz = fminf(fmaxf(fmaf(pz, 128.0f, 127.5f), 0.0f), 255.0f);
    float fx = floorf(ix), fy = floorf(iy), fz = floorf(iz);
    float wx = ix - fx, wy = iy - fy, wz = iz - fz;
    int x0 = (int)fx, y0 = (int)fy, z0 = (int)fz;
    int xb = min(x0, SIDE - 2);
    bool xhi = (x0 > xb);
    int y1 = min(y0 + 1, SIDE - 1);
    int z1 = min(z0 + 1, SIDE - 1);
    float ux = 1.0f - wx, uy = 1.0f - wy, uz = 1.0f - wz;
    float w00 = uz * uy, w01 = uz * wy, w10 = wz * uy, w11 = wz * wy;
    size_t b00 = ((size_t)(z0 * SIDE + y0)) * SIDE + xb;
    size_t b01 = ((size_t)(z0 * SIDE + y1)) * SIDE + xb;
    size_t b10 = ((size_t)(z1 * SIDE + y0)) * SIDE + xb;
    size_t b11 = ((size_t)(z1 * SIDE + y1)) * SIDE + xb;
    float r[4];
#pragma unroll
    for (int c = 0; c < 4; ++c) {
        const float* v = vox + (size_t)c * CHAN_STRIDE;
        f2_unal q00 = *(const f2_unal*)(v + b00);
        f2_unal q01 = *(const f2_unal*)(v + b01);
        f2_unal q10 = *(const f2_unal*)(v + b10);
        f2_unal q11 = *(const f2_unal*)(v + b11);
        float a00 = xhi ? q00.y : q00.x;
        float a01 = xhi ? q01.y : q01.x;
        float a10 = xhi ? q10.y : q10.x;
        float a11 = xhi ? q11.y : q11.x;
        r[c] = w00 * fmaf(a00, ux, q00.y * wx)
             + w01 * fmaf(a01, ux, q01.y * wx)
             + w10 * fmaf(a10, ux, q10.y * wx)
             + w11 * fmaf(a11, ux, q11.y * wx);
    }
    return make_float4(r[0] + bias.x, r[1] + bias.y, r[2] + bias.z, r[3] + bias.w);
}

// ---------------- pass 1: bin points by (z/7, y/7, x-half) tile ------------
__global__ __launch_bounds__(256) void bin_kernel(
    const float* __restrict__ pos, int n,
    int* __restrict__ gcnt, uint4* __restrict__ recs,
    const float* __restrict__ vox, const float* __restrict__ biasp,
    float4* __restrict__ out)
{
    __shared__ int hist[NTILES];
    __shared__ int base[NTILES];
    int tid = threadIdx.x;
    for (int b = tid; b < NTILES; b += 256) hist[b] = 0;
    __syncthreads();

    size_t start = ((size_t)blockIdx.x * 256 + tid) * PPT;
    float buf[3 * PPT];
    bool full = (start + PPT <= (size_t)n);
    if (full) {
        const float4* p4 = (const float4*)(pos + 3 * start);  // 96B, 16B-aligned
#pragma unroll
        for (int k = 0; k < 3 * PPT / 4; ++k) ((float4*)buf)[k] = p4[k];
    } else {
#pragma unroll
        for (int k = 0; k < 3 * PPT; ++k) {
            size_t e = 3 * start + k;
            buf[k] = (e < 3 * (size_t)n) ? pos[e] : 0.0f;
        }
    }

    int bin[PPT], rank[PPT];
#pragma unroll
    for (int j = 0; j < PPT; ++j) {
        bin[j] = -1;
        if (start + j < (size_t)n) {
            float px = buf[3 * j + 0];
            float py = buf[3 * j + 1];
            float pz = buf[3 * j + 2];
            float ixf = fminf(fmaxf(fmaf(px, 128.0f, 127.5f), 0.0f), 255.0f);
            float iyf = fminf(fmaxf(fmaf(py, 128.0f, 127.5f), 0.0f), 255.0f);
            float izf = fminf(fmaxf(fmaf(pz, 128.0f, 127.5f), 0.0f), 255.0f);
            int xt = (ixf >= 128.0f) ? 1 : 0;      // x0 >= 128
            int y0 = (int)floorf(iyf);
            int z0 = (int)floorf(izf);
            bin[j] = ((z0 / ZR) * NTY + (y0 / YR)) * 2 + xt;
            rank[j] = atomicAdd(&hist[bin[j]], 1);
        }
    }
    __syncthreads();
    for (int b = tid; b < NTILES; b += 256)
        base[b] = hist[b] ? atomicAdd(&gcnt[b * CNT_STRIDE], hist[b]) : 0;
    __syncthreads();

    float4 bias = *(const float4*)biasp;
#pragma unroll
    for (int j = 0; j < PPT; ++j) {
        if (bin[j] < 0) continue;
        int slot = base[bin[j]] + rank[j];
        if (slot < CAP) {
            uint4 r;
            r.x = __float_as_uint(buf[3 * j + 0]);
            r.y = __float_as_uint(buf[3 * j + 1]);
            r.z = __float_as_uint(buf[3 * j + 2]);
            r.w = (unsigned)(start + j);
            recs[(size_t)bin[j] * CAP + slot] = r;
        } else {
            // overflow: sample directly -- no point can ever be dropped
            out[start + j] = sample_one(buf[3 * j + 0], buf[3 * j + 1],
                                        buf[3 * j + 2], vox, bias);
        }
    }
}

// ---------------- pass 2: stage 65 KB fp16 tile, sample from LDS -----------
// 512 threads, 65 KB LDS -> 2 blocks/CU; one tile per block; block turnover
// overlaps block i's sample with block i+1's stage.
__global__ __launch_bounds__(BLK, 4) void sample_tiles_kernel(
    const uint4* __restrict__ recs, const int* __restrict__ gcnt,
    const float* __restrict__ vox, const float* __restrict__ biasp,
    float4* __restrict__ out)
{
    __shared__ _Float16 tile[ROWS * COLS * 4];  // 66,560 B

    float4 bias = *(const float4*)biasp;
    int tid = threadIdx.x;
    int t = blockIdx.x;

    int xt = t & 1;
    int rest = t >> 1;
    int zt = rest / NTY, yt = rest - zt * NTY;
    int zbase = zt * ZR, ybase = yt * YR;
    int xbase = xt ? 126 : 0;   // staged cols [xbase, xbase+129]

    // ---- stage: 64 rows x 65 x-pairs, f32->fp16, coalesced ----
    for (int q = tid; q < ROWS * (COLS / 2); q += BLK) {
        int p = q % (COLS / 2);         // x-pair 0..64
        int rowp = q / (COLS / 2);      // 0..63
        int r = rowp & 7, pl = rowp >> 3;
        int zp = min(zbase + pl, SIDE - 1);
        int yp = min(ybase + r, SIDE - 1);
        size_t gbase = ((size_t)(zp * SIDE + yp)) * SIDE + xbase + 2 * p;
        float2 f0 = *(const float2*)(vox + gbase);
        float2 f1 = *(const float2*)(vox + CHAN_STRIDE + gbase);
        float2 f2 = *(const float2*)(vox + 2 * CHAN_STRIDE + gbase);
        float2 f3 = *(const float2*)(vox + 3 * CHAN_STRIDE + gbase);
        h8_al o;
        o[0] = (_Float16)f0.x; o[1] = (_Float16)f1.x;
        o[2] = (_Float16)f2.x; o[3] = (_Float16)f3.x;
        o[4] = (_Float16)f0.y; o[5] = (_Float16)f1.y;
        o[6] = (_Float16)f2.y; o[7] = (_Float16)f3.y;
        *(h8_al*)(tile + rowp * (COLS * 4) + p * 8) = o;  // 16B-aligned
    }
    __syncthreads();

    // ---- sample this tile's points from LDS ----
    int cnt = min(gcnt[t * CNT_STRIDE], CAP);
    const uint4* rec = recs + (size_t)t * CAP;
    for (int r = tid; r < cnt; r += BLK) {
        uint4 R = rec[r];
        float px = __uint_as_float(R.x);
        float py = __uint_as_float(R.y);
        float pz = __uint_as_float(R.z);

        float ix = fminf(fmaxf(fmaf(px, 128.0f, 127.5f), 0.0f), 255.0f);
        float iy = fminf(fmaxf(fmaf(py, 128.0f, 127.5f), 0.0f), 255.0f);
        float iz = fminf(fmaxf(fmaf(pz, 128.0f, 127.5f), 0.0f), 255.0f);
        float fx = floorf(ix), fy = floorf(iy), fz = floorf(iz);
        float wx = ix - fx, wy = iy - fy, wz = iz - fz;
        int x0 = (int)fx, y0 = (int)fy, z0 = (int)fz;
        int xb = min(x0, SIDE - 2);
        bool xhi = (x0 > xb);
        int y1 = min(y0 + 1, SIDE - 1);
        int z1 = min(z0 + 1, SIDE - 1);

        int zl = z0 - zbase, zl1 = z1 - zbase;   // 0..7
        int yl = y0 - ybase, yl1 = y1 - ybase;   // 0..7
        int xloc = xb - xbase;                   // 0..128

        float ux = 1.0f - wx, uy = 1.0f - wy, uz = 1.0f - wz;
        float w00 = uz * uy, w01 = uz * wy, w10 = wz * uy, w11 = wz * wy;

        const _Float16* tp = tile;
        h8_lds v00 = *(const h8_lds*)(tp + (zl  * 8 + yl ) * (COLS * 4) + xloc * 4);
        h8_lds v01 = *(const h8_lds*)(tp + (zl  * 8 + yl1) * (COLS * 4) + xloc * 4);
        h8_lds v10 = *(const h8_lds*)(tp + (zl1 * 8 + yl ) * (COLS * 4) + xloc * 4);
        h8_lds v11 = *(const h8_lds*)(tp + (zl1 * 8 + yl1) * (COLS * 4) + xloc * 4);

        float acc[4];
#pragma unroll
        for (int c = 0; c < 4; ++c) {
            float lo00 = (float)(xhi ? v00[4 + c] : v00[c]);
            float lo01 = (float)(xhi ? v01[4 + c] : v01[c]);
            float lo10 = (float)(xhi ? v10[4 + c] : v10[c]);
            float lo11 = (float)(xhi ? v11[4 + c] : v11[c]);
            float hi00 = (float)v00[4 + c];
            float hi01 = (float)v01[4 + c];
            float hi10 = (float)v10[4 + c];
            float hi11 = (float)v11[4 + c];
            acc[c] = w00 * fmaf(lo00, ux, hi00 * wx)
                   + w01 * fmaf(lo01, ux, hi01 * wx)
                   + w10 * fmaf(lo10, ux, hi10 * wx)
                   + w11 * fmaf(lo11, ux, hi11 * wx);
        }
        out[R.w] = make_float4(acc[0] + bias.x, acc[1] + bias.y,
                               acc[2] + bias.z, acc[3] + bias.w);
    }
}

// ---------------- fallback: direct (R1, 636 us) ----------------------------
__global__ __launch_bounds__(256) void vox_trilerp_kernel(
    const float* __restrict__ pos, const float* __restrict__ vox,
    const float* __restrict__ biasp, float* __restrict__ out, int n)
{
    int i = blockIdx.x * blockDim.x + threadIdx.x;
    if (i >= n) return;
    float4 bias = *(const float4*)biasp;
    float4 res = sample_one(pos[3 * (size_t)i], pos[3 * (size_t)i + 1],
                            pos[3 * (size_t)i + 2], vox, bias);
    *(float4*)(out + 4 * (size_t)i) = res;
}

extern "C" void kernel_launch(void* const* d_in, const int* in_sizes, int n_in,
                              void* d_out, int out_size, void* d_ws, size_t ws_size,
                              hipStream_t stream) {
    const float* pos  = (const float*)d_in[0];
    const float* vox  = (const float*)d_in[1];
    const float* bias = (const float*)d_in[2];
    float* out = (float*)d_out;

    int n = in_sizes[0] / 3;
    size_t need = (size_t)CNT_BYTES + (size_t)NTILES * CAP * sizeof(uint4); // ~56.3 MB

    if (ws_size >= need && n >= 256 * PPT) {
        int* gcnt = (int*)d_ws;
        uint4* recs = (uint4*)((char*)d_ws + CNT_BYTES);
        hipMemsetAsync(d_ws, 0, CNT_BYTES, stream);
        int grid1 = (n + 256 * PPT - 1) / (256 * PPT);
        bin_kernel<<<grid1, 256, 0, stream>>>(pos, n, gcnt, recs, vox, bias,
                                              (float4*)out);
        sample_tiles_kernel<<<NTILES, BLK, 0, stream>>>(recs, gcnt, vox, bias,
                                                        (float4*)out);
    } else {
        int grid = (n + 255) / 256;
        vox_trilerp_kernel<<<grid, 256, 0, stream>>>(pos, vox, bias, out, n);
    }
}

// Round 11
// 149.503 us; speedup vs baseline: 1.5487x; 1.2936x over previous
//
#include <hip/hip_runtime.h>

// 3D trilinear grid_sample (border, align_corners=False) of (4,256,256,256) f32
// voxels at N points, + bias. Output (N,4) f32.
//
// R11: R6's tile-and-stage sample kernel (best: 172 us) kept VERBATIM; the
// single-shot 1369-bin scatter-write binning (est. 60-70 us: each wave wrote
// 64 records to ~40 different bins = line-granular scatter) is replaced by a
// 2-pass radix with BLOCK-LOCAL LDS REORDER so global record writes are
// coalesced ~880 B runs:
//   pass A: bin by z-stripe (37 bins, ~55 pts/bin/block) -> srecs
//   pass B: per stripe, bin by y-tile (37 bins)          -> trecs (R6 layout)
// Overflow at any level -> direct f32 sample (no point can be dropped).

#define SIDE 256
#define CHAN_STRIDE ((size_t)SIDE * SIDE * SIDE)
#define ZR 7
#define YR 7
#define NS 37                       // z-stripes
#define NTY 37                      // y-tiles per stripe
#define NTILES (NS * NTY)           // 1369
#define CNT_STRIDE 16               // ints -> 64 B per counter
#define PPT 8                       // points per thread in bin passes
#define SCAP 65536                  // stripe cap (border mean 58.6K, +29 sigma)
#define TCAP 3072                   // tile cap (border mean ~1740, +33 sigma)
#define BPS 32                      // pass-B blocks per stripe (32*2048 = 65536)

// ws layout
#define SCNT_OFF 0
#define TCNT_OFF 4096
#define CNT_REGION 98304            // scnt + tcnt, zeroed each call
#define SRECS_OFF CNT_REGION
#define SRECS_BYTES ((size_t)NS * SCAP * 16)
#define TRECS_OFF (SRECS_OFF + SRECS_BYTES)
#define TRECS_BYTES ((size_t)NTILES * TCAP * 16)
#define WS_NEED (TRECS_OFF + TRECS_BYTES)   // ~106 MB

typedef float f2_unal __attribute__((ext_vector_type(2), aligned(4)));
typedef _Float16 h8_lds __attribute__((ext_vector_type(8), aligned(8)));
typedef _Float16 h8_al  __attribute__((ext_vector_type(8), aligned(16)));

// ---------------- f32 global sampling (R1, proven) -------------------------
__device__ __forceinline__ float4 sample_one(
    float px, float py, float pz,
    const float* __restrict__ vox, float4 bias)
{
    float ix = fminf(fmaxf(fmaf(px, 128.0f, 127.5f), 0.0f), 255.0f);
    float iy = fminf(fmaxf(fmaf(py, 128.0f, 127.5f), 0.0f), 255.0f);
    float iz = fminf(fmaxf(fmaf(pz, 128.0f, 127.5f), 0.0f), 255.0f);
    float fx = floorf(ix), fy = floorf(iy), fz = floorf(iz);
    float wx = ix - fx, wy = iy - fy, wz = iz - fz;
    int x0 = (int)fx, y0 = (int)fy, z0 = (int)fz;
    int xb = min(x0, SIDE - 2);
    bool xhi = (x0 > xb);
    int y1 = min(y0 + 1, SIDE - 1);
    int z1 = min(z0 + 1, SIDE - 1);
    float ux = 1.0f - wx, uy = 1.0f - wy, uz = 1.0f - wz;
    float w00 = uz * uy, w01 = uz * wy, w10 = wz * uy, w11 = wz * wy;
    size_t b00 = ((size_t)(z0 * SIDE + y0)) * SIDE + xb;
    size_t b01 = ((size_t)(z0 * SIDE + y1)) * SIDE + xb;
    size_t b10 = ((size_t)(z1 * SIDE + y0)) * SIDE + xb;
    size_t b11 = ((size_t)(z1 * SIDE + y1)) * SIDE + xb;
    float r[4];
#pragma unroll
    for (int c = 0; c < 4; ++c) {
        const float* v = vox + (size_t)c * CHAN_STRIDE;
        f2_unal q00 = *(const f2_unal*)(v + b00);
        f2_unal q01 = *(const f2_unal*)(v + b01);
        f2_unal q10 = *(const f2_unal*)(v + b10);
        f2_unal q11 = *(const f2_unal*)(v + b11);
        float a00 = xhi ? q00.y : q00.x;
        float a01 = xhi ? q01.y : q01.x;
        float a10 = xhi ? q10.y : q10.x;
        float a11 = xhi ? q11.y : q11.x;
        r[c] = w00 * fmaf(a00, ux, q00.y * wx)
             + w01 * fmaf(a01, ux, q01.y * wx)
             + w10 * fmaf(a10, ux, q10.y * wx)
             + w11 * fmaf(a11, ux, q11.y * wx);
    }
    return make_float4(r[0] + bias.x, r[1] + bias.y, r[2] + bias.z, r[3] + bias.w);
}

// ---------------- pass A: bin by z-stripe, LDS reorder, coalesced write ----
__global__ __launch_bounds__(256) void binA_kernel(
    const float* __restrict__ pos, int n,
    int* __restrict__ scnt, uint4* __restrict__ srecs,
    const float* __restrict__ vox, const float* __restrict__ biasp,
    float4* __restrict__ out)
{
    __shared__ int hist[NS], pref[NS + 1], gbase[NS];
    __shared__ uint4 sbuf[256 * PPT];
    __shared__ short sbin[256 * PPT];
    int tid = threadIdx.x;
    if (tid < NS) hist[tid] = 0;
    __syncthreads();

    size_t start = ((size_t)blockIdx.x * 256 + tid) * PPT;
    float buf[3 * PPT];
    bool full = (start + PPT <= (size_t)n);
    if (full) {
        const float4* p4 = (const float4*)(pos + 3 * start);
#pragma unroll
        for (int k = 0; k < 3 * PPT / 4; ++k) ((float4*)buf)[k] = p4[k];
    } else {
#pragma unroll
        for (int k = 0; k < 3 * PPT; ++k) {
            size_t e = 3 * start + k;
            buf[k] = (e < 3 * (size_t)n) ? pos[e] : 0.0f;
        }
    }

    int bin[PPT], rank[PPT];
#pragma unroll
    for (int j = 0; j < PPT; ++j) {
        bin[j] = -1;
        if (start + j < (size_t)n) {
            float pz = buf[3 * j + 2];
            float izf = fminf(fmaxf(fmaf(pz, 128.0f, 127.5f), 0.0f), 255.0f);
            int zs = ((int)floorf(izf)) / ZR;
            bin[j] = zs;
            rank[j] = atomicAdd(&hist[zs], 1);
        }
    }
    __syncthreads();
    if (tid == 0) {
        int s = 0;
#pragma unroll
        for (int b = 0; b < NS; ++b) { pref[b] = s; s += hist[b]; }
        pref[NS] = s;
    }
    __syncthreads();
#pragma unroll
    for (int j = 0; j < PPT; ++j) {
        if (bin[j] < 0) continue;
        int slot = pref[bin[j]] + rank[j];
        uint4 r;
        r.x = __float_as_uint(buf[3 * j + 0]);
        r.y = __float_as_uint(buf[3 * j + 1]);
        r.z = __float_as_uint(buf[3 * j + 2]);
        r.w = (unsigned)(start + j);
        sbuf[slot] = r;
        sbin[slot] = (short)bin[j];
    }
    if (tid < NS) gbase[tid] = hist[tid] ? atomicAdd(&scnt[tid * CNT_STRIDE], hist[tid]) : 0;
    __syncthreads();

    int tot = pref[NS];
    float4 bias = *(const float4*)biasp;
    for (int k = tid; k < tot; k += 256) {
        int b = sbin[k];
        int dst = gbase[b] + (k - pref[b]);
        uint4 r = sbuf[k];
        if (dst < SCAP) {
            srecs[(size_t)b * SCAP + dst] = r;   // coalesced ~880B runs
        } else {
            out[r.w] = sample_one(__uint_as_float(r.x), __uint_as_float(r.y),
                                  __uint_as_float(r.z), vox, bias);
        }
    }
}

// ---------------- pass B: per stripe, bin by y-tile, coalesced write -------
__global__ __launch_bounds__(256) void binB_kernel(
    const int* __restrict__ scnt, const uint4* __restrict__ srecs,
    int* __restrict__ tcnt, uint4* __restrict__ trecs,
    const float* __restrict__ vox, const float* __restrict__ biasp,
    float4* __restrict__ out)
{
    __shared__ int hist[NTY], pref[NTY + 1], gbase[NTY];
    __shared__ uint4 sbuf[256 * PPT];
    __shared__ short sbin[256 * PPT];
    int tid = threadIdx.x;
    int s = blockIdx.x / BPS, blk = blockIdx.x % BPS;
    int cnt = min(scnt[s * CNT_STRIDE], SCAP);
    int base = blk * 256 * PPT;
    if (tid < NTY) hist[tid] = 0;
    __syncthreads();

    uint4 R[PPT];
    int bin[PPT], rank[PPT];
#pragma unroll
    for (int j = 0; j < PPT; ++j) {
        bin[j] = -1;
        int ridx = base + j * 256 + tid;         // coalesced 1KB/wave
        if (ridx < cnt) {
            R[j] = srecs[(size_t)s * SCAP + ridx];
            float py = __uint_as_float(R[j].y);
            float iyf = fminf(fmaxf(fmaf(py, 128.0f, 127.5f), 0.0f), 255.0f);
            int yt = ((int)floorf(iyf)) / YR;
            bin[j] = yt;
            rank[j] = atomicAdd(&hist[yt], 1);
        }
    }
    __syncthreads();
    if (tid == 0) {
        int t = 0;
#pragma unroll
        for (int b = 0; b < NTY; ++b) { pref[b] = t; t += hist[b]; }
        pref[NTY] = t;
    }
    __syncthreads();
#pragma unroll
    for (int j = 0; j < PPT; ++j) {
        if (bin[j] < 0) continue;
        int slot = pref[bin[j]] + rank[j];
        sbuf[slot] = R[j];
        sbin[slot] = (short)bin[j];
    }
    if (tid < NTY)
        gbase[tid] = hist[tid]
            ? atomicAdd(&tcnt[(s * NTY + tid) * CNT_STRIDE], hist[tid]) : 0;
    __syncthreads();

    int tot = pref[NTY];
    float4 bias = *(const float4*)biasp;
    for (int k = tid; k < tot; k += 256) {
        int b = sbin[k];
        int dst = gbase[b] + (k - pref[b]);
        uint4 r = sbuf[k];
        if (dst < TCAP) {
            trecs[(size_t)(s * NTY + b) * TCAP + dst] = r;
        } else {
            out[r.w] = sample_one(__uint_as_float(r.x), __uint_as_float(r.y),
                                  __uint_as_float(r.z), vox, bias);
        }
    }
}

// ---------------- sample pass: R6 verbatim (128 KB fp16 tile) --------------
__global__ __launch_bounds__(1024) void sample_tiles_kernel(
    const uint4* __restrict__ trecs, const int* __restrict__ tcnt,
    const float* __restrict__ vox, const float* __restrict__ biasp,
    float4* __restrict__ out)
{
    __shared__ _Float16 tile[8 * 8 * 256 * 4];  // 128 KiB

    float4 bias = *(const float4*)biasp;
    int tid = threadIdx.x;

    for (int t = blockIdx.x; t < NTILES; t += gridDim.x) {
        int zt = t / NTY, yt = t - zt * NTY;
        int zbase = zt * ZR, ybase = yt * YR;

#pragma unroll
        for (int it = 0; it < 8; ++it) {
            int q = it * 1024 + tid;        // 0..8191
            int p = q & 127;                // x-pair index
            int rowp = q >> 7;              // 0..63
            int r = rowp & 7, pl = rowp >> 3;
            int zp = min(zbase + pl, SIDE - 1);
            int yp = min(ybase + r, SIDE - 1);
            size_t gbase = ((size_t)(zp * SIDE + yp)) * SIDE + p * 2;
            float2 f0 = *(const float2*)(vox + gbase);
            float2 f1 = *(const float2*)(vox + CHAN_STRIDE + gbase);
            float2 f2 = *(const float2*)(vox + 2 * CHAN_STRIDE + gbase);
            float2 f3 = *(const float2*)(vox + 3 * CHAN_STRIDE + gbase);
            h8_al o;
            o[0] = (_Float16)f0.x; o[1] = (_Float16)f1.x;
            o[2] = (_Float16)f2.x; o[3] = (_Float16)f3.x;
            o[4] = (_Float16)f0.y; o[5] = (_Float16)f1.y;
            o[6] = (_Float16)f2.y; o[7] = (_Float16)f3.y;
            *(h8_al*)(tile + ((size_t)rowp * 256 + p * 2) * 4) = o;
        }
        __syncthreads();

        int cnt = min(tcnt[t * CNT_STRIDE], TCAP);
        const uint4* rec = trecs + (size_t)t * TCAP;
        for (int r = tid; r < cnt; r += 1024) {
            uint4 R = rec[r];
            float px = __uint_as_float(R.x);
            float py = __uint_as_float(R.y);
            float pz = __uint_as_float(R.z);

            float ix = fminf(fmaxf(fmaf(px, 128.0f, 127.5f), 0.0f), 255.0f);
            float iy = fminf(fmaxf(fmaf(py, 128.0f, 127.5f), 0.0f), 255.0f);
            float iz = fminf(fmaxf(fmaf(pz, 128.0f, 127.5f), 0.0f), 255.0f);
            float fx = floorf(ix), fy = floorf(iy), fz = floorf(iz);
            float wx = ix - fx, wy = iy - fy, wz = iz - fz;
            int x0 = (int)fx, y0 = (int)fy, z0 = (int)fz;
            int xb = min(x0, SIDE - 2);
            bool xhi = (x0 > xb);
            int y1 = min(y0 + 1, SIDE - 1);
            int z1 = min(z0 + 1, SIDE - 1);

            int zl = z0 - zbase, zl1 = z1 - zbase;
            int yl = y0 - ybase, yl1 = y1 - ybase;

            float ux = 1.0f - wx, uy = 1.0f - wy, uz = 1.0f - wz;
            float w00 = uz * uy, w01 = uz * wy, w10 = wz * uy, w11 = wz * wy;

            h8_lds v00 = *(const h8_lds*)(tile + ((zl  * 8 + yl ) * 256 + xb) * 4);
            h8_lds v01 = *(const h8_lds*)(tile + ((zl  * 8 + yl1) * 256 + xb) * 4);
            h8_lds v10 = *(const h8_lds*)(tile + ((zl1 * 8 + yl ) * 256 + xb) * 4);
            h8_lds v11 = *(const h8_lds*)(tile + ((zl1 * 8 + yl1) * 256 + xb) * 4);

            float acc[4];
#pragma unroll
            for (int c = 0; c < 4; ++c) {
                float lo00 = (float)(xhi ? v00[4 + c] : v00[c]);
                float lo01 = (float)(xhi ? v01[4 + c] : v01[c]);
                float lo10 = (float)(xhi ? v10[4 + c] : v10[c]);
                float lo11 = (float)(xhi ? v11[4 + c] : v11[c]);
                float hi00 = (float)v00[4 + c];
                float hi01 = (float)v01[4 + c];
                float hi10 = (float)v10[4 + c];
                float hi11 = (float)v11[4 + c];
                acc[c] = w00 * fmaf(lo00, ux, hi00 * wx)
                       + w01 * fmaf(lo01, ux, hi01 * wx)
                       + w10 * fmaf(lo10, ux, hi10 * wx)
                       + w11 * fmaf(lo11, ux, hi11 * wx);
            }
            out[R.w] = make_float4(acc[0] + bias.x, acc[1] + bias.y,
                                   acc[2] + bias.z, acc[3] + bias.w);
        }
        __syncthreads();
    }
}

// ---------------- fallback: direct (R1, 636 us) ----------------------------
__global__ __launch_bounds__(256) void vox_trilerp_kernel(
    const float* __restrict__ pos, const float* __restrict__ vox,
    const float* __restrict__ biasp, float* __restrict__ out, int n)
{
    int i = blockIdx.x * blockDim.x + threadIdx.x;
    if (i >= n) return;
    float4 bias = *(const float4*)biasp;
    float4 res = sample_one(pos[3 * (size_t)i], pos[3 * (size_t)i + 1],
                            pos[3 * (size_t)i + 2], vox, bias);
    *(float4*)(out + 4 * (size_t)i) = res;
}

extern "C" void kernel_launch(void* const* d_in, const int* in_sizes, int n_in,
                              void* d_out, int out_size, void* d_ws, size_t ws_size,
                              hipStream_t stream) {
    const float* pos  = (const float*)d_in[0];
    const float* vox  = (const float*)d_in[1];
    const float* bias = (const float*)d_in[2];
    float* out = (float*)d_out;

    int n = in_sizes[0] / 3;

    if (ws_size >= WS_NEED && n >= 256 * PPT) {
        int* scnt    = (int*)((char*)d_ws + SCNT_OFF);
        int* tcnt    = (int*)((char*)d_ws + TCNT_OFF);
        uint4* srecs = (uint4*)((char*)d_ws + SRECS_OFF);
        uint4* trecs = (uint4*)((char*)d_ws + TRECS_OFF);
        hipMemsetAsync(d_ws, 0, CNT_REGION, stream);
        int grid1 = (n + 256 * PPT - 1) / (256 * PPT);
        binA_kernel<<<grid1, 256, 0, stream>>>(pos, n, scnt, srecs, vox, bias,
                                               (float4*)out);
        binB_kernel<<<NS * BPS, 256, 0, stream>>>(scnt, srecs, tcnt, trecs,
                                                  vox, bias, (float4*)out);
        sample_tiles_kernel<<<NTILES, 1024, 0, stream>>>(trecs, tcnt, vox, bias,
                                                         (float4*)out);
    } else {
        int grid = (n + 255) / 256;
        vox_trilerp_kernel<<<grid, 256, 0, stream>>>(pos, vox, bias, out, n);
    }
}